// Round 15
// baseline (148.491 us; speedup 1.0000x reference)
//
#include <hip/hip_runtime.h>
#include <math.h>

#define NB 4
#define NN 196
#define NC 64
#define ND0 800
#define NH 5
#define NO1 100
#define NC1 500   // heads*O1 = 5*100
#define NO2 64
#define TT 2      // targets per k_adj block
#define JC 4      // j-chunks per k_adj block
#define JW 200    // j per chunk (JC*JW == ND0)
#define RT 7      // rows per uv-role block (NN = 28*7)
#define RW 2      // rows per proj-role block
#define NEGF -1000000000.0f
#define TH_MARGIN 0.002f

// ---------------- K1 (fused): uv role (NB*28*4 blocks) + proj1 role (NB*98 blocks)
__global__ void __launch_bounds__(256)
k_head(const float* __restrict__ latent,
       const float* __restrict__ w1, const float* __restrict__ b1,
       const float* __restrict__ wl, const float* __restrict__ bl,
       const float* __restrict__ wr, const float* __restrict__ br,
       double* __restrict__ U_d, double* __restrict__ V_d,
       float* __restrict__ U_f, float* __restrict__ VT_f,
       float* __restrict__ xl1, float* __restrict__ xl1T, float* __restrict__ xr1,
       int* __restrict__ bcount) {
    __shared__ double rowd[RT][NC];
    __shared__ float  rowf[RW][NC];
    int bi = blockIdx.x;
    int tid = threadIdx.x;
    if (bi == 0 && tid == 0) *bcount = 0;
    const int NUV = NB*(NN/RT)*4;          // 448
    if (bi < NUV) {
        int b = bi / ((NN/RT)*4);
        int rem = bi % ((NN/RT)*4);
        int tile = rem >> 2;
        int q = rem & 3;
        int n0 = tile * RT;
        for (int idx = tid; idx < RT*NC; idx += 256) {
            int r = idx >> 6, c = idx & 63;
            int n = n0 + r;
            double div = exp((double)(2*(c >> 1)) * (-log(10000.0) / (double)NC));
            double ang = (double)n * div;
            double pe = (c & 1) ? cos(ang) : sin(ang);
            rowd[r][c] = (double)latent[(b*NC + c)*NN + n] + pe;
        }
        __syncthreads();
        int j = q*200 + tid;
        if (tid < 200) {
            double au[RT], av[RT];
            double bb = (double)b1[j];
            #pragma unroll
            for (int r = 0; r < RT; ++r) { au[r] = 0.0; av[r] = bb; }
            #pragma unroll 4
            for (int k = 0; k < NC; ++k) {
                double wu = (double)w1[k*ND0 + j];
                double wv = (double)w1[(NC + k)*ND0 + j];
                #pragma unroll
                for (int r = 0; r < RT; ++r) {
                    au[r] += rowd[r][k] * wu;
                    av[r] += rowd[r][k] * wv;
                }
            }
            size_t bn0 = (size_t)(b*NN + n0);
            #pragma unroll
            for (int r = 0; r < RT; ++r) {
                U_d[(bn0 + r)*ND0 + j] = au[r];
                V_d[(bn0 + r)*ND0 + j] = av[r];
                U_f[(bn0 + r)*ND0 + j] = (float)au[r];
                VT_f[((size_t)b*ND0 + j)*NN + n0 + r] = (float)av[r];
            }
        }
    } else {
        int bn2 = bi - NUV;
        int b = bn2 / (NN/RW);
        int n0 = (bn2 % (NN/RW)) * RW;
        for (int idx = tid; idx < RW*NC; idx += 256) {
            int r = idx >> 6, c = idx & 63;
            int n = n0 + r;
            double div = exp((double)(2*(c >> 1)) * (-log(10000.0) / (double)NC));
            double ang = (double)n * div;
            double pe = (c & 1) ? cos(ang) : sin(ang);
            rowf[r][c] = (float)((double)latent[(b*NC + c)*NN + n] + pe);
        }
        __syncthreads();
        for (int c = tid; c < NC1; c += 256) {
            float al0 = bl[c], ar0 = br[c];
            float al1 = al0, ar1 = ar0;
            #pragma unroll 8
            for (int k = 0; k < NC; ++k) {
                float wlk = wl[k*NC1 + c];
                float wrk = wr[k*NC1 + c];
                float p0 = rowf[0][k], p1 = rowf[1][k];
                al0 += p0 * wlk; al1 += p1 * wlk;
                ar0 += p0 * wrk; ar1 += p1 * wrk;
            }
            size_t bn0 = (size_t)(b*NN + n0);
            xl1[bn0*NC1 + c] = al0;
            xl1[(bn0 + 1)*NC1 + c] = al1;
            xr1[bn0*NC1 + c] = ar0;
            xr1[(bn0 + 1)*NC1 + c] = ar1;
            xl1T[((size_t)b*NC1 + c)*256 + n0] = al0;
            xl1T[((size_t)b*NC1 + c)*256 + n0 + 1] = al1;
        }
    }
}

// ---------------- K3a: f32 adj MLP + gumbel margin -> WT + borderline list
// No LDS staging: U/w2 read via wave-uniform addresses (scalar path / L1 broadcast).
__global__ void __launch_bounds__(1024)
k_adj32(const float* __restrict__ U_f, const float* __restrict__ VT,
        const float* __restrict__ w2, const float* __restrict__ b2,
        const float* __restrict__ gum, float* __restrict__ WT,
        int* __restrict__ blist, int* __restrict__ bcount) {
    __shared__ float part[JC][TT][256];     // 8 KB
    int bi = blockIdx.x;
    int b = bi / (NN/TT);
    int t0 = (bi % (NN/TT)) * TT;
    int tid = threadIdx.x;
    int s = tid & 255;
    int chunk = tid >> 8;
    const float* u0p = U_f + ((size_t)(b*NN + t0))*ND0 + chunk*JW;
    const float* u1p = u0p + ND0;
    const float* w2p = w2 + chunk*JW;
    const float* vp  = VT + ((size_t)b*ND0 + chunk*JW)*NN + s;
    float a0 = 0.0f, a1 = 0.0f;
    if (s < NN) {
        #pragma unroll 4
        for (int jj = 0; jj < JW; ++jj) {
            float v = vp[(size_t)jj*NN];
            float w = w2p[jj];
            float h0 = u0p[jj] + v; h0 = (h0 >= 0.0f) ? h0 : 0.01f*h0; a0 = fmaf(h0, w, a0);
            float h1 = u1p[jj] + v; h1 = (h1 >= 0.0f) ? h1 : 0.01f*h1; a1 = fmaf(h1, w, a1);
        }
    }
    part[chunk][0][s] = a0;
    part[chunk][1][s] = a1;
    __syncthreads();
    if (tid < TT*NN) {
        int tt = tid / NN, ss = tid - tt*NN;
        float acc = b2[0] + part[0][tt][ss] + part[1][tt][ss]
                  + part[2][tt][ss] + part[3][tt][ss];
        int t = t0 + tt;
        float adj = 1.0f/(1.0f + expf(-acc));
        float l1 = logf(fmaxf(adj, 1e-4f));
        float l0 = logf(fmaxf(1.0f - adj, 1e-4f));
        float g0 = gum[((size_t)(b*NN + t)*NN + ss)*2 + 0];
        float g1 = gum[((size_t)(b*NN + t)*NN + ss)*2 + 1];
        float margin = (l1 + g1) - (l0 + g0);
        if (fabsf(margin) <= TH_MARGIN) {
            int li = atomicAdd(bcount, 1);
            blist[li] = (b*NN + t)*NN + ss;
        }
        WT[((size_t)(b*NN + ss))*NN + t] = (margin > 0.0f) ? adj : 0.0f;
    }
}

// ---------------- K3b: f64 exact recompute for borderline pairs (one pair per wave)
__global__ void __launch_bounds__(256)
k_adjfix(const double* __restrict__ U, const double* __restrict__ V,
         const float* __restrict__ w2, const float* __restrict__ b2,
         const float* __restrict__ gum, const int* __restrict__ blist,
         const int* __restrict__ bcount, float* __restrict__ WT) {
    int nfix = *bcount;
    int gwid = (blockIdx.x * blockDim.x + threadIdx.x) >> 6;
    int lane = threadIdx.x & 63;
    int nw = (gridDim.x * blockDim.x) >> 6;
    for (int i = gwid; i < nfix; i += nw) {
        int code = blist[i];
        int s = code % NN;
        int t = (code / NN) % NN;
        int b = code / (NN*NN);
        const double* up = U + ((size_t)(b*NN + t))*ND0;
        const double* vp = V + ((size_t)(b*NN + s))*ND0;
        double a = 0.0;
        for (int j = lane; j < ND0; j += 64) {
            double h = up[j] + vp[j];
            h = (h >= 0.0) ? h : 0.01*h;
            a += h * (double)w2[j];
        }
        for (int off = 32; off >= 1; off >>= 1) a += __shfl_xor(a, off);
        if (lane == 0) {
            double acc = a + (double)b2[0];
            double adj = 1.0/(1.0 + exp(-acc));
            double l1 = log(fmax(adj, 1e-4));
            double l0 = log(fmax(1.0 - adj, 1e-4));
            double g0 = (double)gum[((size_t)(b*NN + t)*NN + s)*2 + 0];
            double g1 = (double)gum[((size_t)(b*NN + t)*NN + s)*2 + 1];
            double z0 = l0 + g0, z1 = l1 + g1;
            double m = fmax(z0, z1);
            double e0 = exp(z0 - m), e1 = exp(z1 - m);
            double sm = e0 + e1;
            int cg = (e1/sm) > (e0/sm);
            WT[((size_t)(b*NN + s))*NN + t] = cg ? (float)adj : 0.0f;
        }
    }
}

// ---------------- K5a: GAT1 logits + softmax, 2 targets/block -> alphaG[(b*NH+h)*NN+t][s]
__global__ void __launch_bounds__(256)
k_gat1a(const float* __restrict__ xl1T, const float* __restrict__ xr1,
        const float* __restrict__ WT, const float* __restrict__ we,
        const float* __restrict__ att, float* __restrict__ alphaG) {
    __shared__ float wred[4][2];
    __shared__ float mxs[2], sms[2];
    int blk = blockIdx.x;          // (b*NH + h)*(NN/2) + tp
    int tp = blk % (NN/2);
    int bh = blk / (NN/2);
    int h = bh % NH;
    int b = bh / NH;
    int t0 = tp*2;
    int s = threadIdx.x;
    int lane = s & 63, wid = s >> 6;
    float wt0 = (s < NN) ? WT[((size_t)(b*NN + t0))*NN + s] : 0.0f;
    float wt1 = (s < NN) ? WT[((size_t)(b*NN + t0 + 1))*NN + s] : 0.0f;
    const float* xT  = xl1T + ((size_t)b*NC1 + h*NO1)*256;
    const float* xr0 = xr1 + ((size_t)(b*NN + t0))*NC1 + h*NO1;
    const float* xr1p= xr1 + ((size_t)(b*NN + t0 + 1))*NC1 + h*NO1;
    const float* weh = we + h*NO1;
    const float* ath = att + h*NO1;
    float a0 = 0.0f, a1 = 0.0f;
    #pragma unroll 5
    for (int o = 0; o < NO1; ++o) {
        float x = xT[(size_t)o*256 + s];
        float w = weh[o];
        float av = ath[o];
        float av2 = 0.2f*av;
        float v0 = fmaf(wt0, w, x + xr0[o]);
        float v1 = fmaf(wt1, w, x + xr1p[o]);
        a0 += fmaxf(v0, 0.0f)*av + fminf(v0, 0.0f)*av2;
        a1 += fmaxf(v1, 0.0f)*av + fminf(v1, 0.0f)*av2;
    }
    bool on0 = (s < NN) && (wt0 != 0.0f);
    bool on1 = (s < NN) && (wt1 != 0.0f);
    float m0 = on0 ? a0 : NEGF;
    float m1 = on1 ? a1 : NEGF;
    #pragma unroll
    for (int off = 32; off >= 1; off >>= 1) {
        m0 = fmaxf(m0, __shfl_xor(m0, off));
        m1 = fmaxf(m1, __shfl_xor(m1, off));
    }
    if (lane == 0) { wred[wid][0] = m0; wred[wid][1] = m1; }
    __syncthreads();
    if (s < 2) mxs[s] = fmaxf(fmaxf(wred[0][s], wred[1][s]), fmaxf(wred[2][s], wred[3][s]));
    __syncthreads();
    float e0 = on0 ? expf(a0 - mxs[0]) : 0.0f;
    float e1 = on1 ? expf(a1 - mxs[1]) : 0.0f;
    float r0 = e0, r1 = e1;
    #pragma unroll
    for (int off = 32; off >= 1; off >>= 1) {
        r0 += __shfl_xor(r0, off);
        r1 += __shfl_xor(r1, off);
    }
    if (lane == 0) { wred[wid][0] = r0; wred[wid][1] = r1; }
    __syncthreads();
    if (s < 2) sms[s] = wred[0][s] + wred[1][s] + wred[2][s] + wred[3][s];
    __syncthreads();
    alphaG[((size_t)bh*NN + t0)*256 + s]     = (sms[0] > 0.0f) ? e0 / sms[0] : 0.0f;
    alphaG[((size_t)bh*NN + t0 + 1)*256 + s] = (sms[1] > 0.0f) ? e1 / sms[1] : 0.0f;
}

// ---------------- K5b+K6 fused: GAT1 aggregate (2 targets) + GAT2 head-0 projections
__global__ void __launch_bounds__(640)
k_gat1bp(const float* __restrict__ xl1, const float* __restrict__ alphaG,
         const float* __restrict__ bias,
         const float* __restrict__ wl2, const float* __restrict__ bl2,
         const float* __restrict__ wr2, const float* __restrict__ br2,
         float* __restrict__ xl2, float* __restrict__ xl2T, float* __restrict__ xr2) {
    __shared__ float row[2][NC1 + 4];
    __shared__ float part[2][2][5][NO2];
    int blk = blockIdx.x;
    int b = blk / (NN/2), tp = blk % (NN/2);
    int t0 = tp*2;
    int tid = threadIdx.x;
    int w = tid >> 6, l = tid & 63;
    int h = w >> 1, csub = w & 1;
    int o = csub*64 + l;
    bool active = (o < NO1);
    int c = h*NO1 + (active ? o : 0);
    const float* ap = alphaG + (((size_t)b*NH + h)*NN + t0)*256;
    const float* xp = xl1 + (size_t)b*NN*NC1 + c;
    float a0 = 0.f, a1 = 0.f;
    for (int s = 0; s < NN; ++s) {
        float x = xp[(size_t)s*NC1];
        a0 = fmaf(ap[s], x, a0);
        a1 = fmaf(ap[256 + s], x, a1);
    }
    if (active) {
        float bs = bias[c];
        float v0 = a0 + bs; row[0][c] = (v0 >= 0.f) ? v0 : 0.01f*v0;
        float v1 = a1 + bs; row[1][c] = (v1 >= 0.f) ? v1 : 0.01f*v1;
    }
    __syncthreads();
    int which = tid / 320;
    int t5 = tid - which*320;
    int seg = t5 >> 6;
    int oo = t5 & 63;
    const float* wmat = which ? wr2 : wl2;
    float p0 = 0.f, p1 = 0.f;
    for (int k = seg*100; k < seg*100 + 100; ++k) {
        float wv = wmat[(size_t)k*320 + oo];
        p0 = fmaf(row[0][k], wv, p0);
        p1 = fmaf(row[1][k], wv, p1);
    }
    part[0][which][seg][oo] = p0;
    part[1][which][seg][oo] = p1;
    __syncthreads();
    if (tid < 256) {
        int r = tid >> 7;
        int wh = (tid >> 6) & 1;
        int o2 = tid & 63;
        float tot = part[r][wh][0][o2] + part[r][wh][1][o2] + part[r][wh][2][o2]
                  + part[r][wh][3][o2] + part[r][wh][4][o2];
        int n = t0 + r;
        size_t bn = (size_t)(b*NN + n);
        if (wh == 0) {
            float vv = tot + bl2[o2];
            xl2[bn*NO2 + o2] = vv;
            xl2T[((size_t)b*NO2 + o2)*256 + n] = vv;
        } else {
            xr2[bn*NO2 + o2] = tot + br2[o2];
        }
    }
}

// ---------------- K7: GAT2 head-0 attention + final channel softmax -> out
__global__ void __launch_bounds__(256)
k_gat2(const float* __restrict__ xl2T, const float* __restrict__ xl2,
       const float* __restrict__ xr2, const float* __restrict__ WT,
       const float* __restrict__ we, const float* __restrict__ att,
       const float* __restrict__ bias, float* __restrict__ out) {
    __shared__ float red[256], alpha_l[256], part[4][NO2];
    __shared__ float mxs, sms;
    int blk = blockIdx.x;
    int b = blk / NN, t = blk % NN;
    int s = threadIdx.x;
    float wt = (s < NN) ? WT[((size_t)(b*NN + t))*NN + s] : 0.0f;
    const float* xT = xl2T + (size_t)b*NO2*256;
    const float* xr = xr2 + ((size_t)(b*NN + t))*NO2;
    float acc = 0.0f;
    for (int c = 0; c < NO2; ++c) {
        float x = xT[(size_t)c*256 + s];
        float v = fmaf(wt, we[c], x + xr[c]);
        float av = att[c];
        acc += fmaxf(v, 0.0f)*av + fminf(v, 0.0f)*(0.2f*av);
    }
    bool on = (s < NN) && (wt != 0.0f);
    float lgt = on ? acc : NEGF;
    red[s] = lgt;
    __syncthreads();
    for (int d = 128; d >= 1; d >>= 1) {
        if (s < d) red[s] = fmaxf(red[s], red[s + d]);
        __syncthreads();
    }
    if (s == 0) mxs = red[0];
    __syncthreads();
    float e = on ? expf(acc - mxs) : 0.0f;
    red[s] = e;
    __syncthreads();
    for (int d = 128; d >= 1; d >>= 1) {
        if (s < d) red[s] += red[s + d];
        __syncthreads();
    }
    if (s == 0) sms = red[0];
    __syncthreads();
    alpha_l[s] = (sms > 0.0f) ? e / sms : 0.0f;
    __syncthreads();
    int c = s & 63, sq = s >> 6;
    float pa = 0.0f;
    const float* xp = xl2 + (size_t)b*NN*NO2 + c;
    for (int ss = sq*49; ss < sq*49 + 49; ++ss)
        pa = fmaf(alpha_l[ss], xp[(size_t)ss*NO2], pa);
    part[sq][c] = pa;
    __syncthreads();
    if (s < NO2) {
        float ny = part[0][s] + part[1][s] + part[2][s] + part[3][s] + bias[s];
        float m = ny;
        for (int off = 32; off >= 1; off >>= 1) m = fmaxf(m, __shfl_xor(m, off));
        float ee = expf(ny - m);
        float ssum = ee;
        for (int off = 32; off >= 1; off >>= 1) ssum += __shfl_xor(ssum, off);
        out[((size_t)(b*NN + t))*NO2 + s] = ee / ssum;
    }
}

extern "C" void kernel_launch(void* const* d_in, const int* in_sizes, int n_in,
                              void* d_out, int out_size, void* d_ws, size_t ws_size,
                              hipStream_t stream) {
    const float* latent  = (const float*)d_in[0];
    const float* gum     = (const float*)d_in[1];
    const float* d0_w1   = (const float*)d_in[2];
    const float* d0_b1   = (const float*)d_in[3];
    const float* d0_w2   = (const float*)d_in[4];
    const float* d0_b2   = (const float*)d_in[5];
    const float* g1_wl   = (const float*)d_in[12];
    const float* g1_bl   = (const float*)d_in[13];
    const float* g1_wr   = (const float*)d_in[14];
    const float* g1_br   = (const float*)d_in[15];
    const float* g1_we   = (const float*)d_in[16];
    const float* g1_att  = (const float*)d_in[17];
    const float* g1_bias = (const float*)d_in[18];
    const float* g2_wl   = (const float*)d_in[19];
    const float* g2_bl   = (const float*)d_in[20];
    const float* g2_wr   = (const float*)d_in[21];
    const float* g2_br   = (const float*)d_in[22];
    const float* g2_we   = (const float*)d_in[23];
    const float* g2_att  = (const float*)d_in[24];
    const float* g2_bias = (const float*)d_in[25];
    float* out = (float*)d_out;

    char* ws = (char*)d_ws;
    size_t off = 0;
    auto alloc = [&](size_t bytes) { char* p = ws + off; off += (bytes + 255) & ~(size_t)255; return (void*)p; };
    double* U_d   = (double*)alloc((size_t)NB*NN*ND0*8);
    double* V_d   = (double*)alloc((size_t)NB*NN*ND0*8);
    float*  U_f   = (float*) alloc((size_t)NB*NN*ND0*4);
    float*  VT_f  = (float*) alloc((size_t)NB*ND0*NN*4);
    float*  WT    = (float*) alloc((size_t)NB*NN*NN*4);
    float*  xl1   = (float*) alloc((size_t)NB*NN*NC1*4);
    float*  xl1T  = (float*) alloc((size_t)NB*NC1*256*4);
    float*  xr1   = (float*) alloc((size_t)NB*NN*NC1*4);
    float*  alphaG= (float*) alloc((size_t)NB*NH*NN*256*4);
    float*  xl2   = (float*) alloc((size_t)NB*NN*NO2*4);
    float*  xl2T  = (float*) alloc((size_t)NB*NO2*256*4);
    float*  xr2   = (float*) alloc((size_t)NB*NN*NO2*4);
    int*    blist = (int*)   alloc((size_t)NB*NN*NN*4);
    int*    bcount= (int*)   alloc(256);

    hipLaunchKernelGGL(k_head,   dim3(NB*(NN/RT)*4 + NB*(NN/RW)), dim3(256), 0, stream,
                       latent, d0_w1, d0_b1, g1_wl, g1_bl, g1_wr, g1_br,
                       U_d, V_d, U_f, VT_f, xl1, xl1T, xr1, bcount);
    hipLaunchKernelGGL(k_adj32,  dim3(NB*(NN/TT)),     dim3(1024), 0, stream, U_f, VT_f, d0_w2, d0_b2, gum, WT, blist, bcount);
    hipLaunchKernelGGL(k_adjfix, dim3(256),            dim3(256),  0, stream, U_d, V_d, d0_w2, d0_b2, gum, blist, bcount, WT);
    hipLaunchKernelGGL(k_gat1a,  dim3(NB*NH*(NN/2)),   dim3(256),  0, stream, xl1T, xr1, WT, g1_we, g1_att, alphaG);
    hipLaunchKernelGGL(k_gat1bp, dim3(NB*(NN/2)),      dim3(640),  0, stream, xl1, alphaG, g1_bias,
                       g2_wl, g2_bl, g2_wr, g2_br, xl2, xl2T, xr2);
    hipLaunchKernelGGL(k_gat2,   dim3(NB*NN),          dim3(256),  0, stream, xl2T, xl2, xr2, WT, g2_we, g2_att, g2_bias, out);
}

// Round 16
// 136.719 us; speedup vs baseline: 1.0861x; 1.0861x over previous
//
#include <hip/hip_runtime.h>
#include <math.h>

#define NB 4
#define NN 196
#define NC 64
#define ND0 800
#define NH 5
#define NO1 100
#define NC1 500   // heads*O1 = 5*100
#define NO2 64
#define TT 2      // targets per k_adj block
#define JC 4      // j-chunks per k_adj block
#define JW 200    // j per chunk (JC*JW == ND0)
#define RT 7      // rows per uv-role block (NN = 28*7)
#define RW 2      // rows per proj-role block
#define NEGF -1000000000.0f
#define TH_MARGIN 0.002f

// ---------------- K1 (fused): uv role (NB*28*4 blocks) + proj1 role (NB*98 blocks)
__global__ void __launch_bounds__(256)
k_head(const float* __restrict__ latent,
       const float* __restrict__ w1, const float* __restrict__ b1,
       const float* __restrict__ wl, const float* __restrict__ bl,
       const float* __restrict__ wr, const float* __restrict__ br,
       double* __restrict__ U_d, double* __restrict__ V_d,
       float* __restrict__ U_f, float* __restrict__ VT_f,
       float* __restrict__ xl1, float* __restrict__ xl1T, float* __restrict__ xr1) {
    __shared__ double rowd[RT][NC];
    __shared__ float  rowf[RW][NC];
    int bi = blockIdx.x;
    int tid = threadIdx.x;
    const int NUV = NB*(NN/RT)*4;          // 448
    if (bi < NUV) {
        int b = bi / ((NN/RT)*4);
        int rem = bi % ((NN/RT)*4);
        int tile = rem >> 2;
        int q = rem & 3;
        int n0 = tile * RT;
        for (int idx = tid; idx < RT*NC; idx += 256) {
            int r = idx >> 6, c = idx & 63;
            int n = n0 + r;
            double div = exp((double)(2*(c >> 1)) * (-log(10000.0) / (double)NC));
            double ang = (double)n * div;
            double pe = (c & 1) ? cos(ang) : sin(ang);
            rowd[r][c] = (double)latent[(b*NC + c)*NN + n] + pe;
        }
        __syncthreads();
        int j = q*200 + tid;
        if (tid < 200) {
            double au[RT], av[RT];
            double bb = (double)b1[j];
            #pragma unroll
            for (int r = 0; r < RT; ++r) { au[r] = 0.0; av[r] = bb; }
            #pragma unroll 4
            for (int k = 0; k < NC; ++k) {
                double wu = (double)w1[k*ND0 + j];
                double wv = (double)w1[(NC + k)*ND0 + j];
                #pragma unroll
                for (int r = 0; r < RT; ++r) {
                    au[r] += rowd[r][k] * wu;
                    av[r] += rowd[r][k] * wv;
                }
            }
            size_t bn0 = (size_t)(b*NN + n0);
            #pragma unroll
            for (int r = 0; r < RT; ++r) {
                U_d[(bn0 + r)*ND0 + j] = au[r];
                V_d[(bn0 + r)*ND0 + j] = av[r];
                U_f[(bn0 + r)*ND0 + j] = (float)au[r];
                VT_f[((size_t)b*ND0 + j)*NN + n0 + r] = (float)av[r];
            }
        }
    } else {
        int bn2 = bi - NUV;
        int b = bn2 / (NN/RW);
        int n0 = (bn2 % (NN/RW)) * RW;
        for (int idx = tid; idx < RW*NC; idx += 256) {
            int r = idx >> 6, c = idx & 63;
            int n = n0 + r;
            double div = exp((double)(2*(c >> 1)) * (-log(10000.0) / (double)NC));
            double ang = (double)n * div;
            double pe = (c & 1) ? cos(ang) : sin(ang);
            rowf[r][c] = (float)((double)latent[(b*NC + c)*NN + n] + pe);
        }
        __syncthreads();
        for (int c = tid; c < NC1; c += 256) {
            float al0 = bl[c], ar0 = br[c];
            float al1 = al0, ar1 = ar0;
            #pragma unroll 8
            for (int k = 0; k < NC; ++k) {
                float wlk = wl[k*NC1 + c];
                float wrk = wr[k*NC1 + c];
                float p0 = rowf[0][k], p1 = rowf[1][k];
                al0 += p0 * wlk; al1 += p1 * wlk;
                ar0 += p0 * wrk; ar1 += p1 * wrk;
            }
            size_t bn0 = (size_t)(b*NN + n0);
            xl1[bn0*NC1 + c] = al0;
            xl1[(bn0 + 1)*NC1 + c] = al1;
            xr1[bn0*NC1 + c] = ar0;
            xr1[(bn0 + 1)*NC1 + c] = ar1;
            xl1T[((size_t)b*NC1 + c)*256 + n0] = al0;
            xl1T[((size_t)b*NC1 + c)*256 + n0 + 1] = al1;
        }
    }
}

// ---------------- K3: f32 adj MLP + gumbel margin -> WT, with block-local f64 fixup tail
// LDS packed as float4 triples (Ul0, Ul1, w2) -> one ds_read_b128 per j-iteration.
__global__ void __launch_bounds__(1024)
k_adj32(const float* __restrict__ U_f, const float* __restrict__ VT,
        const float* __restrict__ w2, const float* __restrict__ b2,
        const float* __restrict__ gum, float* __restrict__ WT,
        const double* __restrict__ U_d, const double* __restrict__ V_d) {
    __shared__ float4 trip[ND0];            // 12.8 KB
    __shared__ float part[JC][TT][256];     // 8 KB
    __shared__ int   lcount;
    __shared__ int   lpairs[TT*NN];         // 1.6 KB
    int bi = blockIdx.x;
    int b = bi / (NN/TT);
    int t0 = (bi % (NN/TT)) * TT;
    int tid = threadIdx.x;
    int s = tid & 255;
    int chunk = tid >> 8;
    if (tid == 0) lcount = 0;
    {
        const float* u0 = U_f + ((size_t)(b*NN + t0))*ND0;
        const float* u1 = U_f + ((size_t)(b*NN + t0 + 1))*ND0;
        for (int j = tid; j < ND0; j += 1024)
            trip[j] = make_float4(u0[j], u1[j], w2[j], 0.0f);
    }
    __syncthreads();
    float a0 = 0.0f, a1 = 0.0f;
    if (s < NN) {
        const float* vp = VT + ((size_t)b*ND0 + chunk*JW)*NN + s;
        int j0 = chunk*JW;
        #pragma unroll 4
        for (int jj = 0; jj < JW; ++jj) {
            float v = vp[(size_t)jj*NN];
            float4 tr = trip[j0 + jj];
            float h0 = tr.x + v; h0 = (h0 >= 0.0f) ? h0 : 0.01f*h0; a0 = fmaf(h0, tr.z, a0);
            float h1 = tr.y + v; h1 = (h1 >= 0.0f) ? h1 : 0.01f*h1; a1 = fmaf(h1, tr.z, a1);
        }
    }
    part[chunk][0][s] = a0;
    part[chunk][1][s] = a1;
    __syncthreads();
    if (tid < TT*NN) {
        int tt = tid / NN, ss = tid - tt*NN;
        float acc = b2[0] + part[0][tt][ss] + part[1][tt][ss]
                  + part[2][tt][ss] + part[3][tt][ss];
        int t = t0 + tt;
        float adj = 1.0f/(1.0f + expf(-acc));
        float l1 = logf(fmaxf(adj, 1e-4f));
        float l0 = logf(fmaxf(1.0f - adj, 1e-4f));
        float g0 = gum[((size_t)(b*NN + t)*NN + ss)*2 + 0];
        float g1 = gum[((size_t)(b*NN + t)*NN + ss)*2 + 1];
        float margin = (l1 + g1) - (l0 + g0);
        if (fabsf(margin) <= TH_MARGIN) {
            int li = atomicAdd(&lcount, 1);
            lpairs[li] = (tt << 8) | ss;
        }
        WT[((size_t)(b*NN + ss))*NN + t] = (margin > 0.0f) ? adj : 0.0f;
    }
    __syncthreads();
    // ---- block-local f64 exact recompute for borderline pairs (one pair per wave) ----
    int nfx = lcount;
    int wid = tid >> 6, lane = tid & 63;
    for (int i = wid; i < nfx; i += 16) {
        int code = lpairs[i];
        int tt = code >> 8, ss = code & 255;
        int t = t0 + tt;
        const double* up = U_d + ((size_t)(b*NN + t))*ND0;
        const double* vp = V_d + ((size_t)(b*NN + ss))*ND0;
        double a = 0.0;
        for (int j = lane; j < ND0; j += 64) {
            double h = up[j] + vp[j];
            h = (h >= 0.0) ? h : 0.01*h;
            a += h * (double)trip[j].z;
        }
        for (int off = 32; off >= 1; off >>= 1) a += __shfl_xor(a, off);
        if (lane == 0) {
            double acc = a + (double)b2[0];
            double adj = 1.0/(1.0 + exp(-acc));
            double l1 = log(fmax(adj, 1e-4));
            double l0 = log(fmax(1.0 - adj, 1e-4));
            double g0 = (double)gum[((size_t)(b*NN + t)*NN + ss)*2 + 0];
            double g1 = (double)gum[((size_t)(b*NN + t)*NN + ss)*2 + 1];
            double z0 = l0 + g0, z1 = l1 + g1;
            double m = fmax(z0, z1);
            double e0 = exp(z0 - m), e1 = exp(z1 - m);
            double sm = e0 + e1;
            int cg = (e1/sm) > (e0/sm);
            WT[((size_t)(b*NN + ss))*NN + t] = cg ? (float)adj : 0.0f;
        }
    }
}

// ---------------- K5a: GAT1 logits + softmax, 2 targets/block -> alphaG[(b*NH+h)*NN+t][s]
__global__ void __launch_bounds__(256)
k_gat1a(const float* __restrict__ xl1T, const float* __restrict__ xr1,
        const float* __restrict__ WT, const float* __restrict__ we,
        const float* __restrict__ att, float* __restrict__ alphaG) {
    __shared__ float wred[4][2];
    __shared__ float mxs[2], sms[2];
    int blk = blockIdx.x;          // (b*NH + h)*(NN/2) + tp
    int tp = blk % (NN/2);
    int bh = blk / (NN/2);
    int h = bh % NH;
    int b = bh / NH;
    int t0 = tp*2;
    int s = threadIdx.x;
    int lane = s & 63, wid = s >> 6;
    float wt0 = (s < NN) ? WT[((size_t)(b*NN + t0))*NN + s] : 0.0f;
    float wt1 = (s < NN) ? WT[((size_t)(b*NN + t0 + 1))*NN + s] : 0.0f;
    const float* xT  = xl1T + ((size_t)b*NC1 + h*NO1)*256;
    const float* xr0 = xr1 + ((size_t)(b*NN + t0))*NC1 + h*NO1;
    const float* xr1p= xr1 + ((size_t)(b*NN + t0 + 1))*NC1 + h*NO1;
    const float* weh = we + h*NO1;
    const float* ath = att + h*NO1;
    float a0 = 0.0f, a1 = 0.0f;
    #pragma unroll 5
    for (int o = 0; o < NO1; ++o) {
        float x = xT[(size_t)o*256 + s];
        float w = weh[o];
        float av = ath[o];
        float av2 = 0.2f*av;
        float v0 = fmaf(wt0, w, x + xr0[o]);
        float v1 = fmaf(wt1, w, x + xr1p[o]);
        a0 += fmaxf(v0, 0.0f)*av + fminf(v0, 0.0f)*av2;
        a1 += fmaxf(v1, 0.0f)*av + fminf(v1, 0.0f)*av2;
    }
    bool on0 = (s < NN) && (wt0 != 0.0f);
    bool on1 = (s < NN) && (wt1 != 0.0f);
    float m0 = on0 ? a0 : NEGF;
    float m1 = on1 ? a1 : NEGF;
    #pragma unroll
    for (int off = 32; off >= 1; off >>= 1) {
        m0 = fmaxf(m0, __shfl_xor(m0, off));
        m1 = fmaxf(m1, __shfl_xor(m1, off));
    }
    if (lane == 0) { wred[wid][0] = m0; wred[wid][1] = m1; }
    __syncthreads();
    if (s < 2) mxs[s] = fmaxf(fmaxf(wred[0][s], wred[1][s]), fmaxf(wred[2][s], wred[3][s]));
    __syncthreads();
    float e0 = on0 ? expf(a0 - mxs[0]) : 0.0f;
    float e1 = on1 ? expf(a1 - mxs[1]) : 0.0f;
    float r0 = e0, r1 = e1;
    #pragma unroll
    for (int off = 32; off >= 1; off >>= 1) {
        r0 += __shfl_xor(r0, off);
        r1 += __shfl_xor(r1, off);
    }
    if (lane == 0) { wred[wid][0] = r0; wred[wid][1] = r1; }
    __syncthreads();
    if (s < 2) sms[s] = wred[0][s] + wred[1][s] + wred[2][s] + wred[3][s];
    __syncthreads();
    alphaG[((size_t)bh*NN + t0)*256 + s]     = (sms[0] > 0.0f) ? e0 / sms[0] : 0.0f;
    alphaG[((size_t)bh*NN + t0 + 1)*256 + s] = (sms[1] > 0.0f) ? e1 / sms[1] : 0.0f;
}

// ---------------- K5b+K6 fused: GAT1 aggregate (2 targets) + GAT2 head-0 projections
__global__ void __launch_bounds__(640)
k_gat1bp(const float* __restrict__ xl1, const float* __restrict__ alphaG,
         const float* __restrict__ bias,
         const float* __restrict__ wl2, const float* __restrict__ bl2,
         const float* __restrict__ wr2, const float* __restrict__ br2,
         float* __restrict__ xl2, float* __restrict__ xl2T, float* __restrict__ xr2) {
    __shared__ float row[2][NC1 + 4];
    __shared__ float part[2][2][5][NO2];
    int blk = blockIdx.x;
    int b = blk / (NN/2), tp = blk % (NN/2);
    int t0 = tp*2;
    int tid = threadIdx.x;
    int w = tid >> 6, l = tid & 63;
    int h = w >> 1, csub = w & 1;
    int o = csub*64 + l;
    bool active = (o < NO1);
    int c = h*NO1 + (active ? o : 0);
    const float* ap = alphaG + (((size_t)b*NH + h)*NN + t0)*256;
    const float* xp = xl1 + (size_t)b*NN*NC1 + c;
    float a0 = 0.f, a1 = 0.f;
    for (int s = 0; s < NN; ++s) {
        float x = xp[(size_t)s*NC1];
        a0 = fmaf(ap[s], x, a0);
        a1 = fmaf(ap[256 + s], x, a1);
    }
    if (active) {
        float bs = bias[c];
        float v0 = a0 + bs; row[0][c] = (v0 >= 0.f) ? v0 : 0.01f*v0;
        float v1 = a1 + bs; row[1][c] = (v1 >= 0.f) ? v1 : 0.01f*v1;
    }
    __syncthreads();
    int which = tid / 320;
    int t5 = tid - which*320;
    int seg = t5 >> 6;
    int oo = t5 & 63;
    const float* wmat = which ? wr2 : wl2;
    float p0 = 0.f, p1 = 0.f;
    for (int k = seg*100; k < seg*100 + 100; ++k) {
        float wv = wmat[(size_t)k*320 + oo];
        p0 = fmaf(row[0][k], wv, p0);
        p1 = fmaf(row[1][k], wv, p1);
    }
    part[0][which][seg][oo] = p0;
    part[1][which][seg][oo] = p1;
    __syncthreads();
    if (tid < 256) {
        int r = tid >> 7;
        int wh = (tid >> 6) & 1;
        int o2 = tid & 63;
        float tot = part[r][wh][0][o2] + part[r][wh][1][o2] + part[r][wh][2][o2]
                  + part[r][wh][3][o2] + part[r][wh][4][o2];
        int n = t0 + r;
        size_t bn = (size_t)(b*NN + n);
        if (wh == 0) {
            float vv = tot + bl2[o2];
            xl2[bn*NO2 + o2] = vv;
            xl2T[((size_t)b*NO2 + o2)*256 + n] = vv;
        } else {
            xr2[bn*NO2 + o2] = tot + br2[o2];
        }
    }
}

// ---------------- K7: GAT2 head-0 attention + final channel softmax -> out
__global__ void __launch_bounds__(256)
k_gat2(const float* __restrict__ xl2T, const float* __restrict__ xl2,
       const float* __restrict__ xr2, const float* __restrict__ WT,
       const float* __restrict__ we, const float* __restrict__ att,
       const float* __restrict__ bias, float* __restrict__ out) {
    __shared__ float red[256], alpha_l[256], part[4][NO2];
    __shared__ float mxs, sms;
    int blk = blockIdx.x;
    int b = blk / NN, t = blk % NN;
    int s = threadIdx.x;
    float wt = (s < NN) ? WT[((size_t)(b*NN + t))*NN + s] : 0.0f;
    const float* xT = xl2T + (size_t)b*NO2*256;
    const float* xr = xr2 + ((size_t)(b*NN + t))*NO2;
    float acc = 0.0f;
    for (int c = 0; c < NO2; ++c) {
        float x = xT[(size_t)c*256 + s];
        float v = fmaf(wt, we[c], x + xr[c]);
        float av = att[c];
        acc += fmaxf(v, 0.0f)*av + fminf(v, 0.0f)*(0.2f*av);
    }
    bool on = (s < NN) && (wt != 0.0f);
    float lgt = on ? acc : NEGF;
    red[s] = lgt;
    __syncthreads();
    for (int d = 128; d >= 1; d >>= 1) {
        if (s < d) red[s] = fmaxf(red[s], red[s + d]);
        __syncthreads();
    }
    if (s == 0) mxs = red[0];
    __syncthreads();
    float e = on ? expf(acc - mxs) : 0.0f;
    red[s] = e;
    __syncthreads();
    for (int d = 128; d >= 1; d >>= 1) {
        if (s < d) red[s] += red[s + d];
        __syncthreads();
    }
    if (s == 0) sms = red[0];
    __syncthreads();
    alpha_l[s] = (sms > 0.0f) ? e / sms : 0.0f;
    __syncthreads();
    int c = s & 63, sq = s >> 6;
    float pa = 0.0f;
    const float* xp = xl2 + (size_t)b*NN*NO2 + c;
    for (int ss = sq*49; ss < sq*49 + 49; ++ss)
        pa = fmaf(alpha_l[ss], xp[(size_t)ss*NO2], pa);
    part[sq][c] = pa;
    __syncthreads();
    if (s < NO2) {
        float ny = part[0][s] + part[1][s] + part[2][s] + part[3][s] + bias[s];
        float m = ny;
        for (int off = 32; off >= 1; off >>= 1) m = fmaxf(m, __shfl_xor(m, off));
        float ee = expf(ny - m);
        float ssum = ee;
        for (int off = 32; off >= 1; off >>= 1) ssum += __shfl_xor(ssum, off);
        out[((size_t)(b*NN + t))*NO2 + s] = ee / ssum;
    }
}

extern "C" void kernel_launch(void* const* d_in, const int* in_sizes, int n_in,
                              void* d_out, int out_size, void* d_ws, size_t ws_size,
                              hipStream_t stream) {
    const float* latent  = (const float*)d_in[0];
    const float* gum     = (const float*)d_in[1];
    const float* d0_w1   = (const float*)d_in[2];
    const float* d0_b1   = (const float*)d_in[3];
    const float* d0_w2   = (const float*)d_in[4];
    const float* d0_b2   = (const float*)d_in[5];
    const float* g1_wl   = (const float*)d_in[12];
    const float* g1_bl   = (const float*)d_in[13];
    const float* g1_wr   = (const float*)d_in[14];
    const float* g1_br   = (const float*)d_in[15];
    const float* g1_we   = (const float*)d_in[16];
    const float* g1_att  = (const float*)d_in[17];
    const float* g1_bias = (const float*)d_in[18];
    const float* g2_wl   = (const float*)d_in[19];
    const float* g2_bl   = (const float*)d_in[20];
    const float* g2_wr   = (const float*)d_in[21];
    const float* g2_br   = (const float*)d_in[22];
    const float* g2_we   = (const float*)d_in[23];
    const float* g2_att  = (const float*)d_in[24];
    const float* g2_bias = (const float*)d_in[25];
    float* out = (float*)d_out;

    char* ws = (char*)d_ws;
    size_t off = 0;
    auto alloc = [&](size_t bytes) { char* p = ws + off; off += (bytes + 255) & ~(size_t)255; return (void*)p; };
    double* U_d   = (double*)alloc((size_t)NB*NN*ND0*8);
    double* V_d   = (double*)alloc((size_t)NB*NN*ND0*8);
    float*  U_f   = (float*) alloc((size_t)NB*NN*ND0*4);
    float*  VT_f  = (float*) alloc((size_t)NB*ND0*NN*4);
    float*  WT    = (float*) alloc((size_t)NB*NN*NN*4);
    float*  xl1   = (float*) alloc((size_t)NB*NN*NC1*4);
    float*  xl1T  = (float*) alloc((size_t)NB*NC1*256*4);
    float*  xr1   = (float*) alloc((size_t)NB*NN*NC1*4);
    float*  alphaG= (float*) alloc((size_t)NB*NH*NN*256*4);
    float*  xl2   = (float*) alloc((size_t)NB*NN*NO2*4);
    float*  xl2T  = (float*) alloc((size_t)NB*NO2*256*4);
    float*  xr2   = (float*) alloc((size_t)NB*NN*NO2*4);

    hipLaunchKernelGGL(k_head,   dim3(NB*(NN/RT)*4 + NB*(NN/RW)), dim3(256), 0, stream,
                       latent, d0_w1, d0_b1, g1_wl, g1_bl, g1_wr, g1_br,
                       U_d, V_d, U_f, VT_f, xl1, xl1T, xr1);
    hipLaunchKernelGGL(k_adj32,  dim3(NB*(NN/TT)),     dim3(1024), 0, stream,
                       U_f, VT_f, d0_w2, d0_b2, gum, WT, U_d, V_d);
    hipLaunchKernelGGL(k_gat1a,  dim3(NB*NH*(NN/2)),   dim3(256),  0, stream, xl1T, xr1, WT, g1_we, g1_att, alphaG);
    hipLaunchKernelGGL(k_gat1bp, dim3(NB*(NN/2)),      dim3(640),  0, stream, xl1, alphaG, g1_bias,
                       g2_wl, g2_bl, g2_wr, g2_br, xl2, xl2T, xr2);
    hipLaunchKernelGGL(k_gat2,   dim3(NB*NN),          dim3(256),  0, stream, xl2T, xl2, xr2, WT, g2_we, g2_att, g2_bias, out);
}

// Round 17
// 134.023 us; speedup vs baseline: 1.1079x; 1.0201x over previous
//
#include <hip/hip_runtime.h>
#include <math.h>

#define NB 4
#define NN 196
#define NC 64
#define ND0 800
#define NH 5
#define NO1 100
#define NC1 500   // heads*O1 = 5*100
#define NO2 64
#define TT 2      // targets per k_adj block
#define JC 4      // j-chunks per k_adj block
#define JW 200    // j per chunk (JC*JW == ND0)
#define RT 7      // rows per uv-role block (NN = 28*7)
#define RW 2      // rows per proj-role block
#define NEGF -1000000000.0f
#define TH_MARGIN 0.002f

// ---------------- K1 (fused): uv role (NB*28*4 blocks) + proj1 role (NB*98 blocks)
__global__ void __launch_bounds__(256)
k_head(const float* __restrict__ latent,
       const float* __restrict__ w1, const float* __restrict__ b1,
       const float* __restrict__ wl, const float* __restrict__ bl,
       const float* __restrict__ wr, const float* __restrict__ br,
       double* __restrict__ U_d, double* __restrict__ V_d,
       float* __restrict__ U_f, float* __restrict__ VT_f,
       float* __restrict__ xl1, float* __restrict__ xl1T, float* __restrict__ xr1,
       int* __restrict__ bcount) {
    __shared__ double rowd[RT][NC];
    __shared__ float  rowf[RW][NC];
    int bi = blockIdx.x;
    int tid = threadIdx.x;
    if (bi == 0 && tid == 0) *bcount = 0;
    const int NUV = NB*(NN/RT)*4;          // 448
    if (bi < NUV) {
        int b = bi / ((NN/RT)*4);
        int rem = bi % ((NN/RT)*4);
        int tile = rem >> 2;
        int q = rem & 3;
        int n0 = tile * RT;
        for (int idx = tid; idx < RT*NC; idx += 256) {
            int r = idx >> 6, c = idx & 63;
            int n = n0 + r;
            double div = exp((double)(2*(c >> 1)) * (-log(10000.0) / (double)NC));
            double ang = (double)n * div;
            double pe = (c & 1) ? cos(ang) : sin(ang);
            rowd[r][c] = (double)latent[(b*NC + c)*NN + n] + pe;
        }
        __syncthreads();
        int j = q*200 + tid;
        if (tid < 200) {
            double au[RT], av[RT];
            double bb = (double)b1[j];
            #pragma unroll
            for (int r = 0; r < RT; ++r) { au[r] = 0.0; av[r] = bb; }
            #pragma unroll 4
            for (int k = 0; k < NC; ++k) {
                double wu = (double)w1[k*ND0 + j];
                double wv = (double)w1[(NC + k)*ND0 + j];
                #pragma unroll
                for (int r = 0; r < RT; ++r) {
                    au[r] += rowd[r][k] * wu;
                    av[r] += rowd[r][k] * wv;
                }
            }
            size_t bn0 = (size_t)(b*NN + n0);
            #pragma unroll
            for (int r = 0; r < RT; ++r) {
                U_d[(bn0 + r)*ND0 + j] = au[r];
                V_d[(bn0 + r)*ND0 + j] = av[r];
                U_f[(bn0 + r)*ND0 + j] = (float)au[r];
                VT_f[((size_t)b*ND0 + j)*NN + n0 + r] = (float)av[r];
            }
        }
    } else {
        int bn2 = bi - NUV;
        int b = bn2 / (NN/RW);
        int n0 = (bn2 % (NN/RW)) * RW;
        for (int idx = tid; idx < RW*NC; idx += 256) {
            int r = idx >> 6, c = idx & 63;
            int n = n0 + r;
            double div = exp((double)(2*(c >> 1)) * (-log(10000.0) / (double)NC));
            double ang = (double)n * div;
            double pe = (c & 1) ? cos(ang) : sin(ang);
            rowf[r][c] = (float)((double)latent[(b*NC + c)*NN + n] + pe);
        }
        __syncthreads();
        for (int c = tid; c < NC1; c += 256) {
            float al0 = bl[c], ar0 = br[c];
            float al1 = al0, ar1 = ar0;
            #pragma unroll 8
            for (int k = 0; k < NC; ++k) {
                float wlk = wl[k*NC1 + c];
                float wrk = wr[k*NC1 + c];
                float p0 = rowf[0][k], p1 = rowf[1][k];
                al0 += p0 * wlk; al1 += p1 * wlk;
                ar0 += p0 * wrk; ar1 += p1 * wrk;
            }
            size_t bn0 = (size_t)(b*NN + n0);
            xl1[bn0*NC1 + c] = al0;
            xl1[(bn0 + 1)*NC1 + c] = al1;
            xr1[bn0*NC1 + c] = ar0;
            xr1[(bn0 + 1)*NC1 + c] = ar1;
            xl1T[((size_t)b*NC1 + c)*256 + n0] = al0;
            xl1T[((size_t)b*NC1 + c)*256 + n0 + 1] = al1;
        }
    }
}

// ---------------- K3a: f32 adj MLP + gumbel margin -> WT + borderline list
// Wave-uniform (u0,u1,w2) kept in register tiles; extracted per-j via v_readlane
// (no LDS on the critical path). j order per chunk is ascending, identical to R14.
__global__ void __launch_bounds__(1024)
k_adj32(const float* __restrict__ U_f, const float* __restrict__ VT,
        const float* __restrict__ w2, const float* __restrict__ b2,
        const float* __restrict__ gum, float* __restrict__ WT,
        int* __restrict__ blist, int* __restrict__ bcount) {
    __shared__ float part[JC][TT][256];     // 8 KB
    int bi = blockIdx.x;
    int b = bi / (NN/TT);
    int t0 = (bi % (NN/TT)) * TT;
    int tid = threadIdx.x;
    int s = tid & 255;
    int chunk = tid >> 8;
    int lane = tid & 63;
    const float* u0p = U_f + ((size_t)(b*NN + t0))*ND0 + chunk*JW;
    const float* u1p = u0p + ND0;
    const float* w2p = w2 + chunk*JW;
    int sc = (s < NN) ? s : (NN - 1);
    const float* vp = VT + ((size_t)b*ND0 + chunk*JW)*NN + sc;
    float a0 = 0.0f, a1 = 0.0f;
    #pragma unroll
    for (int tile = 0; tile < 3; ++tile) {
        int jb = tile*64;
        float u0r = u0p[jb + lane];
        float u1r = u1p[jb + lane];
        float w2r = w2p[jb + lane];
        #pragma unroll
        for (int k = 0; k < 64; ++k) {
            float u0k = __int_as_float(__builtin_amdgcn_readlane(__float_as_int(u0r), k));
            float u1k = __int_as_float(__builtin_amdgcn_readlane(__float_as_int(u1r), k));
            float w2k = __int_as_float(__builtin_amdgcn_readlane(__float_as_int(w2r), k));
            float v = vp[(size_t)(jb + k)*NN];
            float h0 = u0k + v; h0 = (h0 >= 0.0f) ? h0 : 0.01f*h0; a0 = fmaf(h0, w2k, a0);
            float h1 = u1k + v; h1 = (h1 >= 0.0f) ? h1 : 0.01f*h1; a1 = fmaf(h1, w2k, a1);
        }
    }
    {
        float u0r = u0p[192 + (lane & 7)];
        float u1r = u1p[192 + (lane & 7)];
        float w2r = w2p[192 + (lane & 7)];
        #pragma unroll
        for (int k = 0; k < 8; ++k) {
            float u0k = __int_as_float(__builtin_amdgcn_readlane(__float_as_int(u0r), k));
            float u1k = __int_as_float(__builtin_amdgcn_readlane(__float_as_int(u1r), k));
            float w2k = __int_as_float(__builtin_amdgcn_readlane(__float_as_int(w2r), k));
            float v = vp[(size_t)(192 + k)*NN];
            float h0 = u0k + v; h0 = (h0 >= 0.0f) ? h0 : 0.01f*h0; a0 = fmaf(h0, w2k, a0);
            float h1 = u1k + v; h1 = (h1 >= 0.0f) ? h1 : 0.01f*h1; a1 = fmaf(h1, w2k, a1);
        }
    }
    part[chunk][0][s] = a0;
    part[chunk][1][s] = a1;
    __syncthreads();
    if (tid < TT*NN) {
        int tt = tid / NN, ss = tid - tt*NN;
        float acc = b2[0] + part[0][tt][ss] + part[1][tt][ss]
                  + part[2][tt][ss] + part[3][tt][ss];
        int t = t0 + tt;
        float adj = 1.0f/(1.0f + expf(-acc));
        float l1 = logf(fmaxf(adj, 1e-4f));
        float l0 = logf(fmaxf(1.0f - adj, 1e-4f));
        float g0 = gum[((size_t)(b*NN + t)*NN + ss)*2 + 0];
        float g1 = gum[((size_t)(b*NN + t)*NN + ss)*2 + 1];
        float margin = (l1 + g1) - (l0 + g0);
        if (fabsf(margin) <= TH_MARGIN) {
            int li = atomicAdd(bcount, 1);
            blist[li] = (b*NN + t)*NN + ss;
        }
        WT[((size_t)(b*NN + ss))*NN + t] = (margin > 0.0f) ? adj : 0.0f;
    }
}

// ---------------- K3b: f64 exact recompute for borderline pairs (one pair per wave)
__global__ void __launch_bounds__(256)
k_adjfix(const double* __restrict__ U, const double* __restrict__ V,
         const float* __restrict__ w2, const float* __restrict__ b2,
         const float* __restrict__ gum, const int* __restrict__ blist,
         const int* __restrict__ bcount, float* __restrict__ WT) {
    int nfix = *bcount;
    int gwid = (blockIdx.x * blockDim.x + threadIdx.x) >> 6;
    int lane = threadIdx.x & 63;
    int nw = (gridDim.x * blockDim.x) >> 6;
    for (int i = gwid; i < nfix; i += nw) {
        int code = blist[i];
        int s = code % NN;
        int t = (code / NN) % NN;
        int b = code / (NN*NN);
        const double* up = U + ((size_t)(b*NN + t))*ND0;
        const double* vp = V + ((size_t)(b*NN + s))*ND0;
        double a = 0.0;
        for (int j = lane; j < ND0; j += 64) {
            double h = up[j] + vp[j];
            h = (h >= 0.0) ? h : 0.01*h;
            a += h * (double)w2[j];
        }
        for (int off = 32; off >= 1; off >>= 1) a += __shfl_xor(a, off);
        if (lane == 0) {
            double acc = a + (double)b2[0];
            double adj = 1.0/(1.0 + exp(-acc));
            double l1 = log(fmax(adj, 1e-4));
            double l0 = log(fmax(1.0 - adj, 1e-4));
            double g0 = (double)gum[((size_t)(b*NN + t)*NN + s)*2 + 0];
            double g1 = (double)gum[((size_t)(b*NN + t)*NN + s)*2 + 1];
            double z0 = l0 + g0, z1 = l1 + g1;
            double m = fmax(z0, z1);
            double e0 = exp(z0 - m), e1 = exp(z1 - m);
            double sm = e0 + e1;
            int cg = (e1/sm) > (e0/sm);
            WT[((size_t)(b*NN + s))*NN + t] = cg ? (float)adj : 0.0f;
        }
    }
}

// ---------------- K5a: GAT1 logits + softmax, 2 targets/block -> alphaG[(b*NH+h)*NN+t][s]
__global__ void __launch_bounds__(256)
k_gat1a(const float* __restrict__ xl1T, const float* __restrict__ xr1,
        const float* __restrict__ WT, const float* __restrict__ we,
        const float* __restrict__ att, float* __restrict__ alphaG) {
    __shared__ float wred[4][2];
    __shared__ float mxs[2], sms[2];
    int blk = blockIdx.x;          // (b*NH + h)*(NN/2) + tp
    int tp = blk % (NN/2);
    int bh = blk / (NN/2);
    int h = bh % NH;
    int b = bh / NH;
    int t0 = tp*2;
    int s = threadIdx.x;
    int lane = s & 63, wid = s >> 6;
    float wt0 = (s < NN) ? WT[((size_t)(b*NN + t0))*NN + s] : 0.0f;
    float wt1 = (s < NN) ? WT[((size_t)(b*NN + t0 + 1))*NN + s] : 0.0f;
    const float* xT  = xl1T + ((size_t)b*NC1 + h*NO1)*256;
    const float* xr0 = xr1 + ((size_t)(b*NN + t0))*NC1 + h*NO1;
    const float* xr1p= xr1 + ((size_t)(b*NN + t0 + 1))*NC1 + h*NO1;
    const float* weh = we + h*NO1;
    const float* ath = att + h*NO1;
    float a0 = 0.0f, a1 = 0.0f;
    #pragma unroll 5
    for (int o = 0; o < NO1; ++o) {
        float x = xT[(size_t)o*256 + s];
        float w = weh[o];
        float av = ath[o];
        float av2 = 0.2f*av;
        float v0 = fmaf(wt0, w, x + xr0[o]);
        float v1 = fmaf(wt1, w, x + xr1p[o]);
        a0 += fmaxf(v0, 0.0f)*av + fminf(v0, 0.0f)*av2;
        a1 += fmaxf(v1, 0.0f)*av + fminf(v1, 0.0f)*av2;
    }
    bool on0 = (s < NN) && (wt0 != 0.0f);
    bool on1 = (s < NN) && (wt1 != 0.0f);
    float m0 = on0 ? a0 : NEGF;
    float m1 = on1 ? a1 : NEGF;
    #pragma unroll
    for (int off = 32; off >= 1; off >>= 1) {
        m0 = fmaxf(m0, __shfl_xor(m0, off));
        m1 = fmaxf(m1, __shfl_xor(m1, off));
    }
    if (lane == 0) { wred[wid][0] = m0; wred[wid][1] = m1; }
    __syncthreads();
    if (s < 2) mxs[s] = fmaxf(fmaxf(wred[0][s], wred[1][s]), fmaxf(wred[2][s], wred[3][s]));
    __syncthreads();
    float e0 = on0 ? expf(a0 - mxs[0]) : 0.0f;
    float e1 = on1 ? expf(a1 - mxs[1]) : 0.0f;
    float r0 = e0, r1 = e1;
    #pragma unroll
    for (int off = 32; off >= 1; off >>= 1) {
        r0 += __shfl_xor(r0, off);
        r1 += __shfl_xor(r1, off);
    }
    if (lane == 0) { wred[wid][0] = r0; wred[wid][1] = r1; }
    __syncthreads();
    if (s < 2) sms[s] = wred[0][s] + wred[1][s] + wred[2][s] + wred[3][s];
    __syncthreads();
    alphaG[((size_t)bh*NN + t0)*256 + s]     = (sms[0] > 0.0f) ? e0 / sms[0] : 0.0f;
    alphaG[((size_t)bh*NN + t0 + 1)*256 + s] = (sms[1] > 0.0f) ? e1 / sms[1] : 0.0f;
}

// ---------------- K5b+K6 fused: GAT1 aggregate (2 targets) + GAT2 head-0 projections
__global__ void __launch_bounds__(640)
k_gat1bp(const float* __restrict__ xl1, const float* __restrict__ alphaG,
         const float* __restrict__ bias,
         const float* __restrict__ wl2, const float* __restrict__ bl2,
         const float* __restrict__ wr2, const float* __restrict__ br2,
         float* __restrict__ xl2, float* __restrict__ xl2T, float* __restrict__ xr2) {
    __shared__ float row[2][NC1 + 4];
    __shared__ float part[2][2][5][NO2];
    int blk = blockIdx.x;
    int b = blk / (NN/2), tp = blk % (NN/2);
    int t0 = tp*2;
    int tid = threadIdx.x;
    int w = tid >> 6, l = tid & 63;
    int h = w >> 1, csub = w & 1;
    int o = csub*64 + l;
    bool active = (o < NO1);
    int c = h*NO1 + (active ? o : 0);
    const float* ap = alphaG + (((size_t)b*NH + h)*NN + t0)*256;
    const float* xp = xl1 + (size_t)b*NN*NC1 + c;
    float a0 = 0.f, a1 = 0.f;
    for (int s = 0; s < NN; ++s) {
        float x = xp[(size_t)s*NC1];
        a0 = fmaf(ap[s], x, a0);
        a1 = fmaf(ap[256 + s], x, a1);
    }
    if (active) {
        float bs = bias[c];
        float v0 = a0 + bs; row[0][c] = (v0 >= 0.f) ? v0 : 0.01f*v0;
        float v1 = a1 + bs; row[1][c] = (v1 >= 0.f) ? v1 : 0.01f*v1;
    }
    __syncthreads();
    int which = tid / 320;
    int t5 = tid - which*320;
    int seg = t5 >> 6;
    int oo = t5 & 63;
    const float* wmat = which ? wr2 : wl2;
    float p0 = 0.f, p1 = 0.f;
    for (int k = seg*100; k < seg*100 + 100; ++k) {
        float wv = wmat[(size_t)k*320 + oo];
        p0 = fmaf(row[0][k], wv, p0);
        p1 = fmaf(row[1][k], wv, p1);
    }
    part[0][which][seg][oo] = p0;
    part[1][which][seg][oo] = p1;
    __syncthreads();
    if (tid < 256) {
        int r = tid >> 7;
        int wh = (tid >> 6) & 1;
        int o2 = tid & 63;
        float tot = part[r][wh][0][o2] + part[r][wh][1][o2] + part[r][wh][2][o2]
                  + part[r][wh][3][o2] + part[r][wh][4][o2];
        int n = t0 + r;
        size_t bn = (size_t)(b*NN + n);
        if (wh == 0) {
            float vv = tot + bl2[o2];
            xl2[bn*NO2 + o2] = vv;
            xl2T[((size_t)b*NO2 + o2)*256 + n] = vv;
        } else {
            xr2[bn*NO2 + o2] = tot + br2[o2];
        }
    }
}

// ---------------- K7: GAT2 head-0 attention + final channel softmax -> out
__global__ void __launch_bounds__(256)
k_gat2(const float* __restrict__ xl2T, const float* __restrict__ xl2,
       const float* __restrict__ xr2, const float* __restrict__ WT,
       const float* __restrict__ we, const float* __restrict__ att,
       const float* __restrict__ bias, float* __restrict__ out) {
    __shared__ float red[256], alpha_l[256], part[4][NO2];
    __shared__ float mxs, sms;
    int blk = blockIdx.x;
    int b = blk / NN, t = blk % NN;
    int s = threadIdx.x;
    float wt = (s < NN) ? WT[((size_t)(b*NN + t))*NN + s] : 0.0f;
    const float* xT = xl2T + (size_t)b*NO2*256;
    const float* xr = xr2 + ((size_t)(b*NN + t))*NO2;
    float acc = 0.0f;
    for (int c = 0; c < NO2; ++c) {
        float x = xT[(size_t)c*256 + s];
        float v = fmaf(wt, we[c], x + xr[c]);
        float av = att[c];
        acc += fmaxf(v, 0.0f)*av + fminf(v, 0.0f)*(0.2f*av);
    }
    bool on = (s < NN) && (wt != 0.0f);
    float lgt = on ? acc : NEGF;
    red[s] = lgt;
    __syncthreads();
    for (int d = 128; d >= 1; d >>= 1) {
        if (s < d) red[s] = fmaxf(red[s], red[s + d]);
        __syncthreads();
    }
    if (s == 0) mxs = red[0];
    __syncthreads();
    float e = on ? expf(acc - mxs) : 0.0f;
    red[s] = e;
    __syncthreads();
    for (int d = 128; d >= 1; d >>= 1) {
        if (s < d) red[s] += red[s + d];
        __syncthreads();
    }
    if (s == 0) sms = red[0];
    __syncthreads();
    alpha_l[s] = (sms > 0.0f) ? e / sms : 0.0f;
    __syncthreads();
    int c = s & 63, sq = s >> 6;
    float pa = 0.0f;
    const float* xp = xl2 + (size_t)b*NN*NO2 + c;
    for (int ss = sq*49; ss < sq*49 + 49; ++ss)
        pa = fmaf(alpha_l[ss], xp[(size_t)ss*NO2], pa);
    part[sq][c] = pa;
    __syncthreads();
    if (s < NO2) {
        float ny = part[0][s] + part[1][s] + part[2][s] + part[3][s] + bias[s];
        float m = ny;
        for (int off = 32; off >= 1; off >>= 1) m = fmaxf(m, __shfl_xor(m, off));
        float ee = expf(ny - m);
        float ssum = ee;
        for (int off = 32; off >= 1; off >>= 1) ssum += __shfl_xor(ssum, off);
        out[((size_t)(b*NN + t))*NO2 + s] = ee / ssum;
    }
}

extern "C" void kernel_launch(void* const* d_in, const int* in_sizes, int n_in,
                              void* d_out, int out_size, void* d_ws, size_t ws_size,
                              hipStream_t stream) {
    const float* latent  = (const float*)d_in[0];
    const float* gum     = (const float*)d_in[1];
    const float* d0_w1   = (const float*)d_in[2];
    const float* d0_b1   = (const float*)d_in[3];
    const float* d0_w2   = (const float*)d_in[4];
    const float* d0_b2   = (const float*)d_in[5];
    const float* g1_wl   = (const float*)d_in[12];
    const float* g1_bl   = (const float*)d_in[13];
    const float* g1_wr   = (const float*)d_in[14];
    const float* g1_br   = (const float*)d_in[15];
    const float* g1_we   = (const float*)d_in[16];
    const float* g1_att  = (const float*)d_in[17];
    const float* g1_bias = (const float*)d_in[18];
    const float* g2_wl   = (const float*)d_in[19];
    const float* g2_bl   = (const float*)d_in[20];
    const float* g2_wr   = (const float*)d_in[21];
    const float* g2_br   = (const float*)d_in[22];
    const float* g2_we   = (const float*)d_in[23];
    const float* g2_att  = (const float*)d_in[24];
    const float* g2_bias = (const float*)d_in[25];
    float* out = (float*)d_out;

    char* ws = (char*)d_ws;
    size_t off = 0;
    auto alloc = [&](size_t bytes) { char* p = ws + off; off += (bytes + 255) & ~(size_t)255; return (void*)p; };
    double* U_d   = (double*)alloc((size_t)NB*NN*ND0*8);
    double* V_d   = (double*)alloc((size_t)NB*NN*ND0*8);
    float*  U_f   = (float*) alloc((size_t)NB*NN*ND0*4);
    float*  VT_f  = (float*) alloc((size_t)NB*ND0*NN*4);
    float*  WT    = (float*) alloc((size_t)NB*NN*NN*4);
    float*  xl1   = (float*) alloc((size_t)NB*NN*NC1*4);
    float*  xl1T  = (float*) alloc((size_t)NB*NC1*256*4);
    float*  xr1   = (float*) alloc((size_t)NB*NN*NC1*4);
    float*  alphaG= (float*) alloc((size_t)NB*NH*NN*256*4);
    float*  xl2   = (float*) alloc((size_t)NB*NN*NO2*4);
    float*  xl2T  = (float*) alloc((size_t)NB*NO2*256*4);
    float*  xr2   = (float*) alloc((size_t)NB*NN*NO2*4);
    int*    blist = (int*)   alloc((size_t)NB*NN*NN*4);
    int*    bcount= (int*)   alloc(256);

    hipLaunchKernelGGL(k_head,   dim3(NB*(NN/RT)*4 + NB*(NN/RW)), dim3(256), 0, stream,
                       latent, d0_w1, d0_b1, g1_wl, g1_bl, g1_wr, g1_br,
                       U_d, V_d, U_f, VT_f, xl1, xl1T, xr1, bcount);
    hipLaunchKernelGGL(k_adj32,  dim3(NB*(NN/TT)),     dim3(1024), 0, stream, U_f, VT_f, d0_w2, d0_b2, gum, WT, blist, bcount);
    hipLaunchKernelGGL(k_adjfix, dim3(256),            dim3(256),  0, stream, U_d, V_d, d0_w2, d0_b2, gum, blist, bcount, WT);
    hipLaunchKernelGGL(k_gat1a,  dim3(NB*NH*(NN/2)),   dim3(256),  0, stream, xl1T, xr1, WT, g1_we, g1_att, alphaG);
    hipLaunchKernelGGL(k_gat1bp, dim3(NB*(NN/2)),      dim3(640),  0, stream, xl1, alphaG, g1_bias,
                       g2_wl, g2_bl, g2_wr, g2_br, xl2, xl2T, xr2);
    hipLaunchKernelGGL(k_gat2,   dim3(NB*NN),          dim3(256),  0, stream, xl2T, xl2, xr2, WT, g2_we, g2_att, g2_bias, out);
}

// Round 18
// 131.948 us; speedup vs baseline: 1.1254x; 1.0157x over previous
//
#include <hip/hip_runtime.h>
#include <math.h>

#define NB 4
#define NN 196
#define NC 64
#define ND0 800
#define NH 5
#define NO1 100
#define NC1 500   // heads*O1 = 5*100
#define NO2 64
#define TT 2      // targets per k_adj block
#define JC 4      // j-chunks per k_adj block
#define JW 200    // j per chunk (JC*JW == ND0)
#define RT 7      // rows per uv-role block (NN = 28*7)
#define RW 2      // rows per proj-role block
#define NEGF -1000000000.0f
#define TH_MARGIN 0.002f

// ---------------- K1 (fused): uv role (NB*28*4 blocks) + proj1 role (NB*98 blocks)
__global__ void __launch_bounds__(256)
k_head(const float* __restrict__ latent,
       const float* __restrict__ w1, const float* __restrict__ b1,
       const float* __restrict__ wl, const float* __restrict__ bl,
       const float* __restrict__ wr, const float* __restrict__ br,
       double* __restrict__ U_d, double* __restrict__ V_d,
       float* __restrict__ U_f, float* __restrict__ VT_f,
       float* __restrict__ xl1, float* __restrict__ xl1T, float* __restrict__ xr1,
       int* __restrict__ bcount) {
    __shared__ double rowd[RT][NC];
    __shared__ float  rowf[RW][NC];
    int bi = blockIdx.x;
    int tid = threadIdx.x;
    if (bi == 0 && tid == 0) *bcount = 0;
    const int NUV = NB*(NN/RT)*4;          // 448
    if (bi < NUV) {
        int b = bi / ((NN/RT)*4);
        int rem = bi % ((NN/RT)*4);
        int tile = rem >> 2;
        int q = rem & 3;
        int n0 = tile * RT;
        for (int idx = tid; idx < RT*NC; idx += 256) {
            int r = idx >> 6, c = idx & 63;
            int n = n0 + r;
            double div = exp((double)(2*(c >> 1)) * (-log(10000.0) / (double)NC));
            double ang = (double)n * div;
            double pe = (c & 1) ? cos(ang) : sin(ang);
            rowd[r][c] = (double)latent[(b*NC + c)*NN + n] + pe;
        }
        __syncthreads();
        int j = q*200 + tid;
        if (tid < 200) {
            double au[RT], av[RT];
            double bb = (double)b1[j];
            #pragma unroll
            for (int r = 0; r < RT; ++r) { au[r] = 0.0; av[r] = bb; }
            #pragma unroll 4
            for (int k = 0; k < NC; ++k) {
                double wu = (double)w1[k*ND0 + j];
                double wv = (double)w1[(NC + k)*ND0 + j];
                #pragma unroll
                for (int r = 0; r < RT; ++r) {
                    au[r] += rowd[r][k] * wu;
                    av[r] += rowd[r][k] * wv;
                }
            }
            size_t bn0 = (size_t)(b*NN + n0);
            #pragma unroll
            for (int r = 0; r < RT; ++r) {
                U_d[(bn0 + r)*ND0 + j] = au[r];
                V_d[(bn0 + r)*ND0 + j] = av[r];
                U_f[(bn0 + r)*ND0 + j] = (float)au[r];
                VT_f[((size_t)b*ND0 + j)*NN + n0 + r] = (float)av[r];
            }
        }
    } else {
        int bn2 = bi - NUV;
        int b = bn2 / (NN/RW);
        int n0 = (bn2 % (NN/RW)) * RW;
        for (int idx = tid; idx < RW*NC; idx += 256) {
            int r = idx >> 6, c = idx & 63;
            int n = n0 + r;
            double div = exp((double)(2*(c >> 1)) * (-log(10000.0) / (double)NC));
            double ang = (double)n * div;
            double pe = (c & 1) ? cos(ang) : sin(ang);
            rowf[r][c] = (float)((double)latent[(b*NC + c)*NN + n] + pe);
        }
        __syncthreads();
        for (int c = tid; c < NC1; c += 256) {
            float al0 = bl[c], ar0 = br[c];
            float al1 = al0, ar1 = ar0;
            #pragma unroll 8
            for (int k = 0; k < NC; ++k) {
                float wlk = wl[k*NC1 + c];
                float wrk = wr[k*NC1 + c];
                float p0 = rowf[0][k], p1 = rowf[1][k];
                al0 += p0 * wlk; al1 += p1 * wlk;
                ar0 += p0 * wrk; ar1 += p1 * wrk;
            }
            size_t bn0 = (size_t)(b*NN + n0);
            xl1[bn0*NC1 + c] = al0;
            xl1[(bn0 + 1)*NC1 + c] = al1;
            xr1[bn0*NC1 + c] = ar0;
            xr1[(bn0 + 1)*NC1 + c] = ar1;
            xl1T[((size_t)b*NC1 + c)*256 + n0] = al0;
            xl1T[((size_t)b*NC1 + c)*256 + n0 + 1] = al1;
        }
    }
}

// ---------------- K3a: f32 adj MLP + gumbel margin -> WT + borderline list
// LDS packed as float4 triples (Ul0, Ul1, w2) -> one ds_read_b128 per j-iteration.
__global__ void __launch_bounds__(1024)
k_adj32(const float* __restrict__ U_f, const float* __restrict__ VT,
        const float* __restrict__ w2, const float* __restrict__ b2,
        const float* __restrict__ gum, float* __restrict__ WT,
        int* __restrict__ blist, int* __restrict__ bcount) {
    __shared__ float4 trip[ND0];            // 12.8 KB
    __shared__ float part[JC][TT][256];     // 8 KB
    int bi = blockIdx.x;
    int b = bi / (NN/TT);
    int t0 = (bi % (NN/TT)) * TT;
    int tid = threadIdx.x;
    int s = tid & 255;
    int chunk = tid >> 8;
    {
        const float* u0 = U_f + ((size_t)(b*NN + t0))*ND0;
        const float* u1 = U_f + ((size_t)(b*NN + t0 + 1))*ND0;
        for (int j = tid; j < ND0; j += 1024)
            trip[j] = make_float4(u0[j], u1[j], w2[j], 0.0f);
    }
    __syncthreads();
    float a0 = 0.0f, a1 = 0.0f;
    if (s < NN) {
        const float* vp = VT + ((size_t)b*ND0 + chunk*JW)*NN + s;
        int j0 = chunk*JW;
        #pragma unroll 4
        for (int jj = 0; jj < JW; ++jj) {
            float v = vp[(size_t)jj*NN];
            float4 tr = trip[j0 + jj];
            float h0 = tr.x + v; h0 = (h0 >= 0.0f) ? h0 : 0.01f*h0; a0 = fmaf(h0, tr.z, a0);
            float h1 = tr.y + v; h1 = (h1 >= 0.0f) ? h1 : 0.01f*h1; a1 = fmaf(h1, tr.z, a1);
        }
    }
    part[chunk][0][s] = a0;
    part[chunk][1][s] = a1;
    __syncthreads();
    if (tid < TT*NN) {
        int tt = tid / NN, ss = tid - tt*NN;
        float acc = b2[0] + part[0][tt][ss] + part[1][tt][ss]
                  + part[2][tt][ss] + part[3][tt][ss];
        int t = t0 + tt;
        float adj = 1.0f/(1.0f + expf(-acc));
        float l1 = logf(fmaxf(adj, 1e-4f));
        float l0 = logf(fmaxf(1.0f - adj, 1e-4f));
        float g0 = gum[((size_t)(b*NN + t)*NN + ss)*2 + 0];
        float g1 = gum[((size_t)(b*NN + t)*NN + ss)*2 + 1];
        float margin = (l1 + g1) - (l0 + g0);
        if (fabsf(margin) <= TH_MARGIN) {
            int li = atomicAdd(bcount, 1);
            blist[li] = (b*NN + t)*NN + ss;
        }
        WT[((size_t)(b*NN + ss))*NN + t] = (margin > 0.0f) ? adj : 0.0f;
    }
}

// ---------------- K3b: f64 exact recompute for borderline pairs (one pair per wave)
__global__ void __launch_bounds__(256)
k_adjfix(const double* __restrict__ U, const double* __restrict__ V,
         const float* __restrict__ w2, const float* __restrict__ b2,
         const float* __restrict__ gum, const int* __restrict__ blist,
         const int* __restrict__ bcount, float* __restrict__ WT) {
    int nfix = *bcount;
    int gwid = (blockIdx.x * blockDim.x + threadIdx.x) >> 6;
    int lane = threadIdx.x & 63;
    int nw = (gridDim.x * blockDim.x) >> 6;
    for (int i = gwid; i < nfix; i += nw) {
        int code = blist[i];
        int s = code % NN;
        int t = (code / NN) % NN;
        int b = code / (NN*NN);
        const double* up = U + ((size_t)(b*NN + t))*ND0;
        const double* vp = V + ((size_t)(b*NN + s))*ND0;
        double a = 0.0;
        for (int j = lane; j < ND0; j += 64) {
            double h = up[j] + vp[j];
            h = (h >= 0.0) ? h : 0.01*h;
            a += h * (double)w2[j];
        }
        for (int off = 32; off >= 1; off >>= 1) a += __shfl_xor(a, off);
        if (lane == 0) {
            double acc = a + (double)b2[0];
            double adj = 1.0/(1.0 + exp(-acc));
            double l1 = log(fmax(adj, 1e-4));
            double l0 = log(fmax(1.0 - adj, 1e-4));
            double g0 = (double)gum[((size_t)(b*NN + t)*NN + s)*2 + 0];
            double g1 = (double)gum[((size_t)(b*NN + t)*NN + s)*2 + 1];
            double z0 = l0 + g0, z1 = l1 + g1;
            double m = fmax(z0, z1);
            double e0 = exp(z0 - m), e1 = exp(z1 - m);
            double sm = e0 + e1;
            int cg = (e1/sm) > (e0/sm);
            WT[((size_t)(b*NN + s))*NN + t] = cg ? (float)adj : 0.0f;
        }
    }
}

// ---------------- K5a: GAT1 logits + softmax, 2 targets/block -> alphaG[(b*NH+h)*NN+t][s]
__global__ void __launch_bounds__(256)
k_gat1a(const float* __restrict__ xl1T, const float* __restrict__ xr1,
        const float* __restrict__ WT, const float* __restrict__ we,
        const float* __restrict__ att, float* __restrict__ alphaG) {
    __shared__ float wred[4][2];
    __shared__ float mxs[2], sms[2];
    int blk = blockIdx.x;          // (b*NH + h)*(NN/2) + tp
    int tp = blk % (NN/2);
    int bh = blk / (NN/2);
    int h = bh % NH;
    int b = bh / NH;
    int t0 = tp*2;
    int s = threadIdx.x;
    int lane = s & 63, wid = s >> 6;
    float wt0 = (s < NN) ? WT[((size_t)(b*NN + t0))*NN + s] : 0.0f;
    float wt1 = (s < NN) ? WT[((size_t)(b*NN + t0 + 1))*NN + s] : 0.0f;
    const float* xT  = xl1T + ((size_t)b*NC1 + h*NO1)*256;
    const float* xr0 = xr1 + ((size_t)(b*NN + t0))*NC1 + h*NO1;
    const float* xr1p= xr1 + ((size_t)(b*NN + t0 + 1))*NC1 + h*NO1;
    const float* weh = we + h*NO1;
    const float* ath = att + h*NO1;
    float a0 = 0.0f, a1 = 0.0f;
    #pragma unroll 5
    for (int o = 0; o < NO1; ++o) {
        float x = xT[(size_t)o*256 + s];
        float w = weh[o];
        float av = ath[o];
        float av2 = 0.2f*av;
        float v0 = fmaf(wt0, w, x + xr0[o]);
        float v1 = fmaf(wt1, w, x + xr1p[o]);
        a0 += fmaxf(v0, 0.0f)*av + fminf(v0, 0.0f)*av2;
        a1 += fmaxf(v1, 0.0f)*av + fminf(v1, 0.0f)*av2;
    }
    bool on0 = (s < NN) && (wt0 != 0.0f);
    bool on1 = (s < NN) && (wt1 != 0.0f);
    float m0 = on0 ? a0 : NEGF;
    float m1 = on1 ? a1 : NEGF;
    #pragma unroll
    for (int off = 32; off >= 1; off >>= 1) {
        m0 = fmaxf(m0, __shfl_xor(m0, off));
        m1 = fmaxf(m1, __shfl_xor(m1, off));
    }
    if (lane == 0) { wred[wid][0] = m0; wred[wid][1] = m1; }
    __syncthreads();
    if (s < 2) mxs[s] = fmaxf(fmaxf(wred[0][s], wred[1][s]), fmaxf(wred[2][s], wred[3][s]));
    __syncthreads();
    float e0 = on0 ? expf(a0 - mxs[0]) : 0.0f;
    float e1 = on1 ? expf(a1 - mxs[1]) : 0.0f;
    float r0 = e0, r1 = e1;
    #pragma unroll
    for (int off = 32; off >= 1; off >>= 1) {
        r0 += __shfl_xor(r0, off);
        r1 += __shfl_xor(r1, off);
    }
    if (lane == 0) { wred[wid][0] = r0; wred[wid][1] = r1; }
    __syncthreads();
    if (s < 2) sms[s] = wred[0][s] + wred[1][s] + wred[2][s] + wred[3][s];
    __syncthreads();
    alphaG[((size_t)bh*NN + t0)*256 + s]     = (sms[0] > 0.0f) ? e0 / sms[0] : 0.0f;
    alphaG[((size_t)bh*NN + t0 + 1)*256 + s] = (sms[1] > 0.0f) ? e1 / sms[1] : 0.0f;
}

// ---------------- K5b+K6 fused: GAT1 aggregate (2 targets) + GAT2 head-0 projections
__global__ void __launch_bounds__(640)
k_gat1bp(const float* __restrict__ xl1, const float* __restrict__ alphaG,
         const float* __restrict__ bias,
         const float* __restrict__ wl2, const float* __restrict__ bl2,
         const float* __restrict__ wr2, const float* __restrict__ br2,
         float* __restrict__ xl2, float* __restrict__ xl2T, float* __restrict__ xr2) {
    __shared__ float row[2][NC1 + 4];
    __shared__ float part[2][2][5][NO2];
    int blk = blockIdx.x;
    int b = blk / (NN/2), tp = blk % (NN/2);
    int t0 = tp*2;
    int tid = threadIdx.x;
    int w = tid >> 6, l = tid & 63;
    int h = w >> 1, csub = w & 1;
    int o = csub*64 + l;
    bool active = (o < NO1);
    int c = h*NO1 + (active ? o : 0);
    const float* ap = alphaG + (((size_t)b*NH + h)*NN + t0)*256;
    const float* xp = xl1 + (size_t)b*NN*NC1 + c;
    float a0 = 0.f, a1 = 0.f;
    for (int s = 0; s < NN; ++s) {
        float x = xp[(size_t)s*NC1];
        a0 = fmaf(ap[s], x, a0);
        a1 = fmaf(ap[256 + s], x, a1);
    }
    if (active) {
        float bs = bias[c];
        float v0 = a0 + bs; row[0][c] = (v0 >= 0.f) ? v0 : 0.01f*v0;
        float v1 = a1 + bs; row[1][c] = (v1 >= 0.f) ? v1 : 0.01f*v1;
    }
    __syncthreads();
    int which = tid / 320;
    int t5 = tid - which*320;
    int seg = t5 >> 6;
    int oo = t5 & 63;
    const float* wmat = which ? wr2 : wl2;
    float p0 = 0.f, p1 = 0.f;
    for (int k = seg*100; k < seg*100 + 100; ++k) {
        float wv = wmat[(size_t)k*320 + oo];
        p0 = fmaf(row[0][k], wv, p0);
        p1 = fmaf(row[1][k], wv, p1);
    }
    part[0][which][seg][oo] = p0;
    part[1][which][seg][oo] = p1;
    __syncthreads();
    if (tid < 256) {
        int r = tid >> 7;
        int wh = (tid >> 6) & 1;
        int o2 = tid & 63;
        float tot = part[r][wh][0][o2] + part[r][wh][1][o2] + part[r][wh][2][o2]
                  + part[r][wh][3][o2] + part[r][wh][4][o2];
        int n = t0 + r;
        size_t bn = (size_t)(b*NN + n);
        if (wh == 0) {
            float vv = tot + bl2[o2];
            xl2[bn*NO2 + o2] = vv;
            xl2T[((size_t)b*NO2 + o2)*256 + n] = vv;
        } else {
            xr2[bn*NO2 + o2] = tot + br2[o2];
        }
    }
}

// ---------------- K7: GAT2 head-0 attention + final channel softmax -> out
__global__ void __launch_bounds__(256)
k_gat2(const float* __restrict__ xl2T, const float* __restrict__ xl2,
       const float* __restrict__ xr2, const float* __restrict__ WT,
       const float* __restrict__ we, const float* __restrict__ att,
       const float* __restrict__ bias, float* __restrict__ out) {
    __shared__ float red[256], alpha_l[256], part[4][NO2];
    __shared__ float mxs, sms;
    int blk = blockIdx.x;
    int b = blk / NN, t = blk % NN;
    int s = threadIdx.x;
    float wt = (s < NN) ? WT[((size_t)(b*NN + t))*NN + s] : 0.0f;
    const float* xT = xl2T + (size_t)b*NO2*256;
    const float* xr = xr2 + ((size_t)(b*NN + t))*NO2;
    float acc = 0.0f;
    for (int c = 0; c < NO2; ++c) {
        float x = xT[(size_t)c*256 + s];
        float v = fmaf(wt, we[c], x + xr[c]);
        float av = att[c];
        acc += fmaxf(v, 0.0f)*av + fminf(v, 0.0f)*(0.2f*av);
    }
    bool on = (s < NN) && (wt != 0.0f);
    float lgt = on ? acc : NEGF;
    red[s] = lgt;
    __syncthreads();
    for (int d = 128; d >= 1; d >>= 1) {
        if (s < d) red[s] = fmaxf(red[s], red[s + d]);
        __syncthreads();
    }
    if (s == 0) mxs = red[0];
    __syncthreads();
    float e = on ? expf(acc - mxs) : 0.0f;
    red[s] = e;
    __syncthreads();
    for (int d = 128; d >= 1; d >>= 1) {
        if (s < d) red[s] += red[s + d];
        __syncthreads();
    }
    if (s == 0) sms = red[0];
    __syncthreads();
    alpha_l[s] = (sms > 0.0f) ? e / sms : 0.0f;
    __syncthreads();
    int c = s & 63, sq = s >> 6;
    float pa = 0.0f;
    const float* xp = xl2 + (size_t)b*NN*NO2 + c;
    for (int ss = sq*49; ss < sq*49 + 49; ++ss)
        pa = fmaf(alpha_l[ss], xp[(size_t)ss*NO2], pa);
    part[sq][c] = pa;
    __syncthreads();
    if (s < NO2) {
        float ny = part[0][s] + part[1][s] + part[2][s] + part[3][s] + bias[s];
        float m = ny;
        for (int off = 32; off >= 1; off >>= 1) m = fmaxf(m, __shfl_xor(m, off));
        float ee = expf(ny - m);
        float ssum = ee;
        for (int off = 32; off >= 1; off >>= 1) ssum += __shfl_xor(ssum, off);
        out[((size_t)(b*NN + t))*NO2 + s] = ee / ssum;
    }
}

extern "C" void kernel_launch(void* const* d_in, const int* in_sizes, int n_in,
                              void* d_out, int out_size, void* d_ws, size_t ws_size,
                              hipStream_t stream) {
    const float* latent  = (const float*)d_in[0];
    const float* gum     = (const float*)d_in[1];
    const float* d0_w1   = (const float*)d_in[2];
    const float* d0_b1   = (const float*)d_in[3];
    const float* d0_w2   = (const float*)d_in[4];
    const float* d0_b2   = (const float*)d_in[5];
    const float* g1_wl   = (const float*)d_in[12];
    const float* g1_bl   = (const float*)d_in[13];
    const float* g1_wr   = (const float*)d_in[14];
    const float* g1_br   = (const float*)d_in[15];
    const float* g1_we   = (const float*)d_in[16];
    const float* g1_att  = (const float*)d_in[17];
    const float* g1_bias = (const float*)d_in[18];
    const float* g2_wl   = (const float*)d_in[19];
    const float* g2_bl   = (const float*)d_in[20];
    const float* g2_wr   = (const float*)d_in[21];
    const float* g2_br   = (const float*)d_in[22];
    const float* g2_we   = (const float*)d_in[23];
    const float* g2_att  = (const float*)d_in[24];
    const float* g2_bias = (const float*)d_in[25];
    float* out = (float*)d_out;

    char* ws = (char*)d_ws;
    size_t off = 0;
    auto alloc = [&](size_t bytes) { char* p = ws + off; off += (bytes + 255) & ~(size_t)255; return (void*)p; };
    double* U_d   = (double*)alloc((size_t)NB*NN*ND0*8);
    double* V_d   = (double*)alloc((size_t)NB*NN*ND0*8);
    float*  U_f   = (float*) alloc((size_t)NB*NN*ND0*4);
    float*  VT_f  = (float*) alloc((size_t)NB*ND0*NN*4);
    float*  WT    = (float*) alloc((size_t)NB*NN*NN*4);
    float*  xl1   = (float*) alloc((size_t)NB*NN*NC1*4);
    float*  xl1T  = (float*) alloc((size_t)NB*NC1*256*4);
    float*  xr1   = (float*) alloc((size_t)NB*NN*NC1*4);
    float*  alphaG= (float*) alloc((size_t)NB*NH*NN*256*4);
    float*  xl2   = (float*) alloc((size_t)NB*NN*NO2*4);
    float*  xl2T  = (float*) alloc((size_t)NB*NO2*256*4);
    float*  xr2   = (float*) alloc((size_t)NB*NN*NO2*4);
    int*    blist = (int*)   alloc((size_t)NB*NN*NN*4);
    int*    bcount= (int*)   alloc(256);

    hipLaunchKernelGGL(k_head,   dim3(NB*(NN/RT)*4 + NB*(NN/RW)), dim3(256), 0, stream,
                       latent, d0_w1, d0_b1, g1_wl, g1_bl, g1_wr, g1_br,
                       U_d, V_d, U_f, VT_f, xl1, xl1T, xr1, bcount);
    hipLaunchKernelGGL(k_adj32,  dim3(NB*(NN/TT)),     dim3(1024), 0, stream, U_f, VT_f, d0_w2, d0_b2, gum, WT, blist, bcount);
    hipLaunchKernelGGL(k_adjfix, dim3(256),            dim3(256),  0, stream, U_d, V_d, d0_w2, d0_b2, gum, blist, bcount, WT);
    hipLaunchKernelGGL(k_gat1a,  dim3(NB*NH*(NN/2)),   dim3(256),  0, stream, xl1T, xr1, WT, g1_we, g1_att, alphaG);
    hipLaunchKernelGGL(k_gat1bp, dim3(NB*(NN/2)),      dim3(640),  0, stream, xl1, alphaG, g1_bias,
                       g2_wl, g2_bl, g2_wr, g2_br, xl2, xl2T, xr2);
    hipLaunchKernelGGL(k_gat2,   dim3(NB*NN),          dim3(256),  0, stream, xl2T, xl2, xr2, WT, g2_we, g2_att, g2_bias, out);
}